// Round 1
// baseline (1071.151 us; speedup 1.0000x reference)
//
#include <hip/hip_runtime.h>

#define NN 16384
#define NCB 8
#define DIM 32
#define CB 1024

// Kernel A: csqb[k*CB+c] = ||codebook[k,c]||^2 + rate_bias[k,c]
__global__ __launch_bounds__(256) void vq_csq(const float* __restrict__ cb,
                                              const float* __restrict__ rb,
                                              float* __restrict__ out) {
    int i = blockIdx.x * 256 + threadIdx.x;
    if (i >= NCB * CB) return;
    const float4* c4 = reinterpret_cast<const float4*>(cb + (size_t)i * DIM);
    float s0 = 0.f, s1 = 0.f, s2 = 0.f, s3 = 0.f;
#pragma unroll
    for (int j = 0; j < 8; ++j) {
        float4 v = c4[j];
        s0 = fmaf(v.x, v.x, s0);
        s1 = fmaf(v.y, v.y, s1);
        s2 = fmaf(v.z, v.z, s2);
        s3 = fmaf(v.w, v.w, s3);
    }
    out[i] = ((s0 + s1) + (s2 + s3)) + rb[i];
}

// Kernel B: per block -> one k, 256 rows of x.
//   Phase 1: zero the block's one_hot slice (coalesced float4 stores; drains in bg)
//   Phase 2: 2 threads per (n,k) pair scan 512 codebook entries each (scalar loads),
//            shfl_xor reduce with first-occurrence tie-break
//   Phase 3: barrier (zero stores acked by now), then scatter 1.0 / x_hat / index
__global__ __launch_bounds__(512) void vq_main(const float* __restrict__ x,
                                               const float* __restrict__ cb,
                                               const float* __restrict__ csqb,
                                               float* __restrict__ xhat,
                                               float* __restrict__ onehot,
                                               float* __restrict__ idxf) {
    const int tid = threadIdx.x;
    const int k = blockIdx.x & (NCB - 1);
    const int tile = blockIdx.x >> 3;
    const int n0 = tile * 256;

    // ---- Phase 1: zero one_hot rows n0..n0+255 for this k ----
    {
        const float4 z = make_float4(0.f, 0.f, 0.f, 0.f);
        const int rh = tid >> 8;    // 0..1: which of 2 rows per iter
        const int col = tid & 255;  // float4 column within the 1024-float row
#pragma unroll 4
        for (int it = 0; it < 128; ++it) {
            const int r = it * 2 + rh;
            float4* row = reinterpret_cast<float4*>(
                onehot + ((size_t)(n0 + r) * NCB + k) * CB);
            row[col] = z;
        }
    }

    // ---- Phase 2: distance scan ----
    const int p = tid >> 1;  // pair id 0..255 -> row
    const int h = tid & 1;   // half of the codebook
    const int n = n0 + p;

    const float4* xp =
        reinterpret_cast<const float4*>(x + ((size_t)n * NCB + k) * DIM);
    float4 xv[8];
#pragma unroll
    for (int j = 0; j < 8; ++j) xv[j] = xp[j];

    float q0 = 0.f, q1 = 0.f, q2 = 0.f, q3 = 0.f;
#pragma unroll
    for (int j = 0; j < 8; ++j) {
        q0 = fmaf(xv[j].x, xv[j].x, q0);
        q1 = fmaf(xv[j].y, xv[j].y, q1);
        q2 = fmaf(xv[j].z, xv[j].z, q2);
        q3 = fmaf(xv[j].w, xv[j].w, q3);
    }
    const float xsq = (q0 + q1) + (q2 + q3);

    const float4* cbp =
        reinterpret_cast<const float4*>(cb + (size_t)k * CB * DIM);
    const float* cq = csqb + k * CB;

    float best = 3.4028235e38f;
    int bi = 0;
    const int c0 = h * 512;
    for (int c = c0; c < c0 + 512; ++c) {
        float d0 = 0.f, d1 = 0.f, d2 = 0.f, d3 = 0.f;
#pragma unroll
        for (int j = 0; j < 8; ++j) {
            float4 a = cbp[(size_t)c * 8 + j];  // wave-uniform -> scalar loads
            d0 = fmaf(xv[j].x, a.x, d0);
            d1 = fmaf(xv[j].y, a.y, d1);
            d2 = fmaf(xv[j].z, a.z, d2);
            d3 = fmaf(xv[j].w, a.w, d3);
        }
        const float dot = (d0 + d1) + (d2 + d3);
        const float dist = fmaf(-2.f, dot, xsq + cq[c]);
        if (dist < best) {  // strict < keeps first occurrence within the half
            best = dist;
            bi = c;
        }
    }

    // reduce across the pair; tie -> smaller index (first occurrence)
    const float ob = __shfl_xor(best, 1);
    const int oi = __shfl_xor(bi, 1);
    if (ob < best || (ob == best && oi < bi)) {
        best = ob;
        bi = oi;
    }

    __syncthreads();  // phase-1 zero stores complete before scatter

    // ---- Phase 3: outputs (even lane of each pair) ----
    if (h == 0) {
        idxf[(size_t)n * NCB + k] = (float)bi;
        const float4* src = cbp + (size_t)bi * 8;
        float4* dst =
            reinterpret_cast<float4*>(xhat + ((size_t)n * NCB + k) * DIM);
#pragma unroll
        for (int j = 0; j < 8; ++j) dst[j] = src[j];
        onehot[((size_t)n * NCB + k) * CB + bi] = 1.0f;
    }
}

extern "C" void kernel_launch(void* const* d_in, const int* in_sizes, int n_in,
                              void* d_out, int out_size, void* d_ws,
                              size_t ws_size, hipStream_t stream) {
    const float* x = (const float*)d_in[0];
    const float* cb = (const float*)d_in[1];
    const float* rb = (const float*)d_in[2];

    float* out = (float*)d_out;
    float* xhat = out;                                    // N*NCB*DIM
    float* onehot = out + (size_t)NN * NCB * DIM;         // N*NCB*CB
    float* idxf = onehot + (size_t)NN * NCB * CB;         // N*NCB

    float* csqb = (float*)d_ws;  // NCB*CB floats = 32 KB

    vq_csq<<<(NCB * CB + 255) / 256, 256, 0, stream>>>(cb, rb, csqb);
    vq_main<<<(NN / 256) * NCB, 512, 0, stream>>>(x, cb, csqb, xhat, onehot,
                                                  idxf);
}

// Round 2
// 259.463 us; speedup vs baseline: 4.1283x; 4.1283x over previous
//
#include <hip/hip_runtime.h>

#define NN 16384
#define NCB 8
#define DIM 32
#define CB 1024
#define TILE 128   // codebook entries per LDS tile
#define ROWS 256   // (n,k) pairs per block
#define NTILES (CB / TILE)

// Kernel A: csqb[k*CB+c] = ||codebook[k,c]||^2 + rate_bias[k,c]
__global__ __launch_bounds__(256) void vq_csq(const float* __restrict__ cb,
                                              const float* __restrict__ rb,
                                              float* __restrict__ out) {
    int i = blockIdx.x * 256 + threadIdx.x;
    if (i >= NCB * CB) return;
    const float4* c4 = reinterpret_cast<const float4*>(cb + (size_t)i * DIM);
    float s0 = 0.f, s1 = 0.f, s2 = 0.f, s3 = 0.f;
#pragma unroll
    for (int j = 0; j < 8; ++j) {
        float4 v = c4[j];
        s0 = fmaf(v.x, v.x, s0);
        s1 = fmaf(v.y, v.y, s1);
        s2 = fmaf(v.z, v.z, s2);
        s3 = fmaf(v.w, v.w, s3);
    }
    out[i] = ((s0 + s1) + (s2 + s3)) + rb[i];
}

// Kernel B: block = one k, 256 rows. LDS-staged codebook tiles (broadcast
// reads), double-buffered with register-staged prefetch; one_hot zero-fill
// interleaved one chunk per tile so stores drain under compute.
__global__ __launch_bounds__(256, 2) void vq_main(const float* __restrict__ x,
                                                  const float* __restrict__ cb,
                                                  const float* __restrict__ csqb,
                                                  float* __restrict__ xhat,
                                                  float* __restrict__ onehot,
                                                  float* __restrict__ idxf) {
    __shared__ float smem[2][TILE * DIM];  // 2 x 16 KB
    __shared__ float scq[2][TILE];         // 2 x 512 B

    const int tid = threadIdx.x;
    const int k = blockIdx.x & (NCB - 1);
    const int n0 = (blockIdx.x >> 3) * ROWS;
    const int n = n0 + tid;

    const float* cbk = cb + (size_t)k * CB * DIM;
    const float* cqk = csqb + k * CB;

    // x row -> registers, ||x||^2 (same chain order as round 1)
    const float4* xp =
        reinterpret_cast<const float4*>(x + ((size_t)n * NCB + k) * DIM);
    float4 xv[8];
#pragma unroll
    for (int j = 0; j < 8; ++j) xv[j] = xp[j];
    float q0 = 0.f, q1 = 0.f, q2 = 0.f, q3 = 0.f;
#pragma unroll
    for (int j = 0; j < 8; ++j) {
        q0 = fmaf(xv[j].x, xv[j].x, q0);
        q1 = fmaf(xv[j].y, xv[j].y, q1);
        q2 = fmaf(xv[j].z, xv[j].z, q2);
        q3 = fmaf(xv[j].w, xv[j].w, q3);
    }
    const float xsq = (q0 + q1) + (q2 + q3);

#define ZEROCHUNK(ch)                                                        \
    do {                                                                     \
        const float4 z_ = make_float4(0.f, 0.f, 0.f, 0.f);                   \
        _Pragma("unroll") for (int it_ = 0; it_ < 32; ++it_) {               \
            float4* row_ = reinterpret_cast<float4*>(                        \
                onehot + ((size_t)(n0 + (ch)*32 + it_) * NCB + k) * CB);     \
            row_[tid] = z_;                                                  \
        }                                                                    \
    } while (0)

    // ---- prologue: stage tile 0, issue zero chunk 0 ----
    float4 st[4];
    {
        const float4* src = reinterpret_cast<const float4*>(cbk);
#pragma unroll
        for (int i = 0; i < 4; ++i) st[i] = src[i * 256 + tid];
        float cqv = (tid < TILE) ? cqk[tid] : 0.f;
        ZEROCHUNK(0);
        float4* dst = reinterpret_cast<float4*>(&smem[0][0]);
#pragma unroll
        for (int i = 0; i < 4; ++i) dst[i * 256 + tid] = st[i];
        if (tid < TILE) scq[0][tid] = cqv;
    }
    __syncthreads();

    float best = 3.4028235e38f;
    int bi = 0;

    for (int t = 0; t < NTILES; ++t) {
        const int b = t & 1;
        float cqv = 0.f;
        if (t < NTILES - 1) {
            // prefetch next tile into registers; issue next zero chunk
            const float4* src = reinterpret_cast<const float4*>(
                cbk + (size_t)(t + 1) * TILE * DIM);
#pragma unroll
            for (int i = 0; i < 4; ++i) st[i] = src[i * 256 + tid];
            if (tid < TILE) cqv = cqk[(t + 1) * TILE + tid];
            ZEROCHUNK(t + 1);
        }

        // ---- compute current tile from LDS (broadcast reads) ----
        const float* bufc = &smem[b][0];
        const float* cqb = &scq[b][0];
#pragma unroll 2
        for (int c = 0; c < TILE; ++c) {
            const float4* e =
                reinterpret_cast<const float4*>(bufc + c * DIM);
            float d0 = 0.f, d1 = 0.f, d2 = 0.f, d3 = 0.f;
#pragma unroll
            for (int j = 0; j < 8; ++j) {
                float4 a = e[j];
                d0 = fmaf(xv[j].x, a.x, d0);
                d1 = fmaf(xv[j].y, a.y, d1);
                d2 = fmaf(xv[j].z, a.z, d2);
                d3 = fmaf(xv[j].w, a.w, d3);
            }
            const float dot = (d0 + d1) + (d2 + d3);
            const float dist = fmaf(-2.f, dot, xsq + cqb[c]);
            const int cg = t * TILE + c;
            if (dist < best) {  // strict < keeps first occurrence
                best = dist;
                bi = cg;
            }
        }

        if (t < NTILES - 1) {
            float4* dst = reinterpret_cast<float4*>(&smem[b ^ 1][0]);
#pragma unroll
            for (int i = 0; i < 4; ++i) dst[i * 256 + tid] = st[i];
            if (tid < TILE) scq[b ^ 1][tid] = cqv;
        }
        __syncthreads();  // stage t+1 visible; zero chunk t+1 acked; buffers safe
    }

    // ---- epilogue: scatter (zeros for our rows are all drained) ----
    idxf[(size_t)n * NCB + k] = (float)bi;
    const float4* src = reinterpret_cast<const float4*>(cbk + (size_t)bi * DIM);
    float4* dst = reinterpret_cast<float4*>(xhat + ((size_t)n * NCB + k) * DIM);
#pragma unroll
    for (int j = 0; j < 8; ++j) dst[j] = src[j];
    onehot[((size_t)n * NCB + k) * CB + bi] = 1.0f;
#undef ZEROCHUNK
}

extern "C" void kernel_launch(void* const* d_in, const int* in_sizes, int n_in,
                              void* d_out, int out_size, void* d_ws,
                              size_t ws_size, hipStream_t stream) {
    const float* x = (const float*)d_in[0];
    const float* cb = (const float*)d_in[1];
    const float* rb = (const float*)d_in[2];

    float* out = (float*)d_out;
    float* xhat = out;                             // N*NCB*DIM
    float* onehot = out + (size_t)NN * NCB * DIM;  // N*NCB*CB
    float* idxf = onehot + (size_t)NN * NCB * CB;  // N*NCB

    float* csqb = (float*)d_ws;  // NCB*CB floats = 32 KB

    vq_csq<<<(NCB * CB + 255) / 256, 256, 0, stream>>>(cb, rb, csqb);
    vq_main<<<(NN / ROWS) * NCB, 256, 0, stream>>>(x, cb, csqb, xhat, onehot,
                                                   idxf);
}

// Round 3
// 214.448 us; speedup vs baseline: 4.9949x; 1.2099x over previous
//
#include <hip/hip_runtime.h>

#define NN 16384
#define NCB 8
#define DIM 32
#define CB 1024
#define TILE 64            // codebook entries per wave-tile
#define NTILES (CB / TILE) // 16
#define RPB 512            // rows per block (one k)
#define NWAVE 4

// Kernel A: csqb[k*CB+c] = ||codebook[k,c]||^2 + rate_bias[k,c]
__global__ __launch_bounds__(256) void vq_csq(const float* __restrict__ cb,
                                              const float* __restrict__ rb,
                                              float* __restrict__ out) {
    int i = blockIdx.x * 256 + threadIdx.x;
    if (i >= NCB * CB) return;
    const float4* c4 = reinterpret_cast<const float4*>(cb + (size_t)i * DIM);
    float s0 = 0.f, s1 = 0.f, s2 = 0.f, s3 = 0.f;
#pragma unroll
    for (int j = 0; j < 8; ++j) {
        float4 v = c4[j];
        s0 = fmaf(v.x, v.x, s0);
        s1 = fmaf(v.y, v.y, s1);
        s2 = fmaf(v.z, v.z, s2);
        s3 = fmaf(v.w, v.w, s3);
    }
    out[i] = ((s0 + s1) + (s2 + s3)) + rb[i];
}

// Fused kernel: 256 blocks (1/CU), block = 4 waves, one k + 512 rows each.
// Per-WAVE private double-buffered LDS codebook tiles -> no __syncthreads in
// the main loop, so the interleaved one_hot zero-stores are never drained by
// a barrier; they retire in the background at HBM write rate while the VALU
// scans. R=2 rows/thread amortizes LDS reads (8 ds_read_b128 per 64 FMAs).
__global__ __launch_bounds__(256) void vq_fused(const float* __restrict__ x,
                                                const float* __restrict__ cb,
                                                const float* __restrict__ csqb,
                                                float* __restrict__ xhat,
                                                float* __restrict__ onehot,
                                                float* __restrict__ idxf) {
    __shared__ float4 sm[NWAVE][2][TILE * 8];  // 4*2*8KB = 64 KB exactly

    const int tid = threadIdx.x;
    const int w = tid >> 6;
    const int lane = tid & 63;
    const int k = blockIdx.x & (NCB - 1);
    const int n0 = (blockIdx.x >> 3) * RPB;

    const float* cbk = cb + (size_t)k * CB * DIM;
    const float4* cbk4 = reinterpret_cast<const float4*>(cbk);
    const float* cqk = csqb + k * CB;

    const int r0 = n0 + w * 64 + lane;
    const int r1 = r0 + 256;

    // x rows -> registers; ||x||^2 with the frozen round-2 chain order
    float4 xa[8], xb[8];
    {
        const float4* p0 =
            reinterpret_cast<const float4*>(x + ((size_t)r0 * NCB + k) * DIM);
        const float4* p1 =
            reinterpret_cast<const float4*>(x + ((size_t)r1 * NCB + k) * DIM);
#pragma unroll
        for (int j = 0; j < 8; ++j) { xa[j] = p0[j]; xb[j] = p1[j]; }
    }
    float xsa, xsb;
    {
        float q0 = 0.f, q1 = 0.f, q2 = 0.f, q3 = 0.f;
#pragma unroll
        for (int j = 0; j < 8; ++j) {
            q0 = fmaf(xa[j].x, xa[j].x, q0);
            q1 = fmaf(xa[j].y, xa[j].y, q1);
            q2 = fmaf(xa[j].z, xa[j].z, q2);
            q3 = fmaf(xa[j].w, xa[j].w, q3);
        }
        xsa = (q0 + q1) + (q2 + q3);
        q0 = q1 = q2 = q3 = 0.f;
#pragma unroll
        for (int j = 0; j < 8; ++j) {
            q0 = fmaf(xb[j].x, xb[j].x, q0);
            q1 = fmaf(xb[j].y, xb[j].y, q1);
            q2 = fmaf(xb[j].z, xb[j].z, q2);
            q3 = fmaf(xb[j].w, xb[j].w, q3);
        }
        xsb = (q0 + q1) + (q2 + q3);
    }

    // prologue: stage tile 0 into this wave's buffer 0
    float4 st[8];
    float cq_cur, cq_nxt = 0.f;
#pragma unroll
    for (int i = 0; i < 8; ++i) st[i] = cbk4[i * 64 + lane];
    cq_cur = cqk[lane];
#pragma unroll
    for (int i = 0; i < 8; ++i) sm[w][0][i * 64 + lane] = st[i];

    float bda = 3.4028235e38f, bdb = 3.4028235e38f;
    int bia = 0, bib = 0;

    float4* oh4 = reinterpret_cast<float4*>(onehot);
    const float4 z4 = make_float4(0.f, 0.f, 0.f, 0.f);

    for (int t = 0; t < NTILES; ++t) {
        const int b = t & 1;

        // prefetch next tile into registers (loads issued before the stores
        // below, so the pre-ds_write wait is a counted vmcnt, not a drain)
        if (t < NTILES - 1) {
#pragma unroll
            for (int i = 0; i < 8; ++i)
                st[i] = cbk4[(t + 1) * (TILE * 8) + i * 64 + lane];
            cq_nxt = cqk[(t + 1) * TILE + lane];
        }

        // zero chunk: 8 rows per wave-phase, fully coalesced 1KB stores
        {
            const int rbase = n0 + (t * NWAVE + w) * 8;
#pragma unroll
            for (int rr = 0; rr < 8; ++rr) {
                const size_t rowb = ((size_t)(rbase + rr) * NCB + k) * 256;
#pragma unroll
                for (int jj = 0; jj < 4; ++jj)
                    oh4[rowb + jj * 64 + lane] = z4;
            }
        }
        __builtin_amdgcn_sched_barrier(0);  // pin stores before compute

        // compute current tile from this wave's LDS (uniform broadcast reads)
        const float4* buf = &sm[w][b][0];
#pragma unroll 2
        for (int c = 0; c < TILE; ++c) {
            const float cqv = __int_as_float(
                __builtin_amdgcn_readlane(__float_as_int(cq_cur), c));
            float4 a0 = buf[c * 8 + 0], a1 = buf[c * 8 + 1];
            float4 a2 = buf[c * 8 + 2], a3 = buf[c * 8 + 3];
            float4 a4 = buf[c * 8 + 4], a5 = buf[c * 8 + 5];
            float4 a6 = buf[c * 8 + 6], a7 = buf[c * 8 + 7];

            // row A (frozen chain order)
            float d0 = 0.f, d1 = 0.f, d2 = 0.f, d3 = 0.f;
            d0 = fmaf(xa[0].x, a0.x, d0); d1 = fmaf(xa[0].y, a0.y, d1);
            d2 = fmaf(xa[0].z, a0.z, d2); d3 = fmaf(xa[0].w, a0.w, d3);
            d0 = fmaf(xa[1].x, a1.x, d0); d1 = fmaf(xa[1].y, a1.y, d1);
            d2 = fmaf(xa[1].z, a1.z, d2); d3 = fmaf(xa[1].w, a1.w, d3);
            d0 = fmaf(xa[2].x, a2.x, d0); d1 = fmaf(xa[2].y, a2.y, d1);
            d2 = fmaf(xa[2].z, a2.z, d2); d3 = fmaf(xa[2].w, a2.w, d3);
            d0 = fmaf(xa[3].x, a3.x, d0); d1 = fmaf(xa[3].y, a3.y, d1);
            d2 = fmaf(xa[3].z, a3.z, d2); d3 = fmaf(xa[3].w, a3.w, d3);
            d0 = fmaf(xa[4].x, a4.x, d0); d1 = fmaf(xa[4].y, a4.y, d1);
            d2 = fmaf(xa[4].z, a4.z, d2); d3 = fmaf(xa[4].w, a4.w, d3);
            d0 = fmaf(xa[5].x, a5.x, d0); d1 = fmaf(xa[5].y, a5.y, d1);
            d2 = fmaf(xa[5].z, a5.z, d2); d3 = fmaf(xa[5].w, a5.w, d3);
            d0 = fmaf(xa[6].x, a6.x, d0); d1 = fmaf(xa[6].y, a6.y, d1);
            d2 = fmaf(xa[6].z, a6.z, d2); d3 = fmaf(xa[6].w, a6.w, d3);
            d0 = fmaf(xa[7].x, a7.x, d0); d1 = fmaf(xa[7].y, a7.y, d1);
            d2 = fmaf(xa[7].z, a7.z, d2); d3 = fmaf(xa[7].w, a7.w, d3);
            {
                const float dot = (d0 + d1) + (d2 + d3);
                const float dist = fmaf(-2.f, dot, xsa + cqv);
                const int cg = t * TILE + c;
                if (dist < bda) { bda = dist; bia = cg; }
            }
            // row B
            d0 = 0.f; d1 = 0.f; d2 = 0.f; d3 = 0.f;
            d0 = fmaf(xb[0].x, a0.x, d0); d1 = fmaf(xb[0].y, a0.y, d1);
            d2 = fmaf(xb[0].z, a0.z, d2); d3 = fmaf(xb[0].w, a0.w, d3);
            d0 = fmaf(xb[1].x, a1.x, d0); d1 = fmaf(xb[1].y, a1.y, d1);
            d2 = fmaf(xb[1].z, a1.z, d2); d3 = fmaf(xb[1].w, a1.w, d3);
            d0 = fmaf(xb[2].x, a2.x, d0); d1 = fmaf(xb[2].y, a2.y, d1);
            d2 = fmaf(xb[2].z, a2.z, d2); d3 = fmaf(xb[2].w, a2.w, d3);
            d0 = fmaf(xb[3].x, a3.x, d0); d1 = fmaf(xb[3].y, a3.y, d1);
            d2 = fmaf(xb[3].z, a3.z, d2); d3 = fmaf(xb[3].w, a3.w, d3);
            d0 = fmaf(xb[4].x, a4.x, d0); d1 = fmaf(xb[4].y, a4.y, d1);
            d2 = fmaf(xb[4].z, a4.z, d2); d3 = fmaf(xb[4].w, a4.w, d3);
            d0 = fmaf(xb[5].x, a5.x, d0); d1 = fmaf(xb[5].y, a5.y, d1);
            d2 = fmaf(xb[5].z, a5.z, d2); d3 = fmaf(xb[5].w, a5.w, d3);
            d0 = fmaf(xb[6].x, a6.x, d0); d1 = fmaf(xb[6].y, a6.y, d1);
            d2 = fmaf(xb[6].z, a6.z, d2); d3 = fmaf(xb[6].w, a6.w, d3);
            d0 = fmaf(xb[7].x, a7.x, d0); d1 = fmaf(xb[7].y, a7.y, d1);
            d2 = fmaf(xb[7].z, a7.z, d2); d3 = fmaf(xb[7].w, a7.w, d3);
            {
                const float dot = (d0 + d1) + (d2 + d3);
                const float dist = fmaf(-2.f, dot, xsb + cqv);
                const int cg = t * TILE + c;
                if (dist < bdb) { bdb = dist; bib = cg; }
            }
        }

        // write staged tile t+1 into the other buffer (same wave -> no barrier)
        if (t < NTILES - 1) {
#pragma unroll
            for (int i = 0; i < 8; ++i) sm[w][b ^ 1][i * 64 + lane] = st[i];
            cq_cur = cq_nxt;
        }
    }

    __syncthreads();  // single drain: all zero-stores done, cross-wave ordered

    // epilogue: index / x_hat / one_hot scatter for both rows
    {
        idxf[(size_t)r0 * NCB + k] = (float)bia;
        const float4* src = cbk4 + (size_t)bia * 8;
        float4* dst =
            reinterpret_cast<float4*>(xhat + ((size_t)r0 * NCB + k) * DIM);
#pragma unroll
        for (int j = 0; j < 8; ++j) dst[j] = src[j];
        onehot[((size_t)r0 * NCB + k) * CB + bia] = 1.0f;
    }
    {
        idxf[(size_t)r1 * NCB + k] = (float)bib;
        const float4* src = cbk4 + (size_t)bib * 8;
        float4* dst =
            reinterpret_cast<float4*>(xhat + ((size_t)r1 * NCB + k) * DIM);
#pragma unroll
        for (int j = 0; j < 8; ++j) dst[j] = src[j];
        onehot[((size_t)r1 * NCB + k) * CB + bib] = 1.0f;
    }
}

extern "C" void kernel_launch(void* const* d_in, const int* in_sizes, int n_in,
                              void* d_out, int out_size, void* d_ws,
                              size_t ws_size, hipStream_t stream) {
    const float* x = (const float*)d_in[0];
    const float* cb = (const float*)d_in[1];
    const float* rb = (const float*)d_in[2];

    float* out = (float*)d_out;
    float* xhat = out;                             // N*NCB*DIM
    float* onehot = out + (size_t)NN * NCB * DIM;  // N*NCB*CB
    float* idxf = onehot + (size_t)NN * NCB * CB;  // N*NCB

    float* csqb = (float*)d_ws;  // NCB*CB floats = 32 KB

    vq_csq<<<(NCB * CB + 255) / 256, 256, 0, stream>>>(cb, rb, csqb);
    vq_fused<<<(NN / RPB) * NCB, 256, 0, stream>>>(x, cb, csqb, xhat, onehot,
                                                   idxf);
}